// Round 17
// baseline (188.114 us; speedup 1.0000x reference)
//
#include <hip/hip_runtime.h>
#include <math.h>

#define F_IN 500
#define F_HID 128
#define F_OUT 47
#define NGRP 8

typedef __attribute__((ext_vector_type(8))) short short8;
typedef __attribute__((ext_vector_type(4))) float f32x4;

__device__ inline unsigned pack_bf16x2(float a, float b) {
    unsigned ua = __float_as_uint(a), ub = __float_as_uint(b);
    ua = (ua + 0x7FFFu + ((ua >> 16) & 1u)) >> 16;
    ub = (ub + 0x7FFFu + ((ub >> 16) & 1u)) >> 16;
    return ua | (ub << 16);
}
__device__ inline unsigned short pack_bf16(float a) {
    unsigned u = __float_as_uint(a);
    return (unsigned short)((u + 0x7FFFu + ((u >> 16) & 1u)) >> 16);
}

// async global->LDS, 16B per lane, dest = wave-uniform base + lane*16
__device__ __forceinline__ void gload_lds16(const void* g, void* l) {
    __builtin_amdgcn_global_load_lds(
        (const __attribute__((address_space(1))) unsigned int*)g,
        (__attribute__((address_space(3))) unsigned int*)l, 16, 0, 0);
}

// ---------------- degree / norm / CSR build ----------------
// XCD-partitioned + int4-vectorized: group g = blockIdx&7 handles dst in its n/8 slice.
__global__ void k_deg_count(const int* __restrict__ ei, int* __restrict__ ecnt,
                            int E, int n) {
    int g = blockIdx.x & (NGRP - 1);
    int bi = blockIdx.x >> 3;
    int nbg = gridDim.x >> 3;
    int lo = (int)((long)g * n / NGRP), hi = (int)((long)(g + 1) * n / NGRP);
    const int4* dst4 = (const int4*)(ei + E);
    int E4 = E >> 2;
    for (int e4 = bi * 256 + threadIdx.x; e4 < E4; e4 += nbg * 256) {
        int4 d = dst4[e4];
        if (d.x >= lo && d.x < hi) atomicAdd(&ecnt[d.x], 1);
        if (d.y >= lo && d.y < hi) atomicAdd(&ecnt[d.y], 1);
        if (d.z >= lo && d.z < hi) atomicAdd(&ecnt[d.z], 1);
        if (d.w >= lo && d.w < hi) atomicAdd(&ecnt[d.w], 1);
    }
    for (int e = E4 * 4 + bi * 256 + threadIdx.x; e < E; e += nbg * 256) {
        int d = ei[E + e];
        if (d >= lo && d < hi) atomicAdd(&ecnt[d], 1);
    }
}

// ---------------- scan phase A (+ dinv fused) ----------------
__global__ __launch_bounds__(1024) void k_scanA(const int* __restrict__ ecnt,
                                                int* __restrict__ rowptr,
                                                int* __restrict__ bsum,
                                                float* __restrict__ dinv, int n) {
    __shared__ int tmp[1024];
    int t = threadIdx.x;
    int gid = blockIdx.x * 1024 + t;
    int v = (gid < n) ? ecnt[gid] : 0;
    if (gid < n) dinv[gid] = rsqrtf((float)(v + 1));  // +1 self-loop
    tmp[t] = v;
    __syncthreads();
    for (int off = 1; off < 1024; off <<= 1) {
        int u = (t >= off) ? tmp[t - off] : 0;
        __syncthreads();
        tmp[t] += u;
        __syncthreads();
    }
    if (gid < n) rowptr[gid] = tmp[t] - v;
    if (t == 1023) bsum[blockIdx.x] = tmp[1023];
}

// ---------------- scan phase C (self-contained: scans bsum per block; nb<=64) ----------
__global__ __launch_bounds__(1024) void k_scanC(int* __restrict__ rowptr,
                                                int* __restrict__ cur,
                                                const int* __restrict__ bsum,
                                                int n, int nb) {
    __shared__ int s_off, s_tot;
    int t = threadIdx.x;
    if (t < 64) {
        int v = (t < nb) ? bsum[t] : 0;
        int inc = v;
#pragma unroll
        for (int off = 1; off < 64; off <<= 1) {
            int u = __shfl_up(inc, off);
            if (t >= off) inc += u;
        }
        if (t == (int)blockIdx.x) s_off = inc - v;  // exclusive offset for this block
        if (t == nb - 1) s_tot = inc;               // grand total
    }
    __syncthreads();
    int gid = blockIdx.x * 1024 + t;
    if (gid < n) {
        int v = rowptr[gid] + s_off;
        rowptr[gid] = v;
        cur[gid] = v;
    } else if (gid == n) {
        rowptr[n] = s_tot;
    }
}

// XCD-partitioned + int4-vectorized CSR fill
__global__ void k_fill(const int* __restrict__ ei, int* __restrict__ cur,
                       int* __restrict__ csr, int E, int n) {
    int g = blockIdx.x & (NGRP - 1);
    int bi = blockIdx.x >> 3;
    int nbg = gridDim.x >> 3;
    int lo = (int)((long)g * n / NGRP), hi = (int)((long)(g + 1) * n / NGRP);
    const int4* dst4 = (const int4*)(ei + E);
    const int4* src4 = (const int4*)ei;
    int E4 = E >> 2;
    for (int e4 = bi * 256 + threadIdx.x; e4 < E4; e4 += nbg * 256) {
        int4 d = dst4[e4];
        int4 s = src4[e4];
        if (d.x >= lo && d.x < hi) csr[atomicAdd(&cur[d.x], 1)] = s.x;
        if (d.y >= lo && d.y < hi) csr[atomicAdd(&cur[d.y], 1)] = s.y;
        if (d.z >= lo && d.z < hi) csr[atomicAdd(&cur[d.z], 1)] = s.z;
        if (d.w >= lo && d.w < hi) csr[atomicAdd(&cur[d.w], 1)] = s.w;
    }
    for (int e = E4 * 4 + bi * 256 + threadIdx.x; e < E; e += nbg * 256) {
        int d = ei[E + e];
        if (d >= lo && d < hi) csr[atomicAdd(&cur[d], 1)] = ei[e];
    }
}

// ---------------- weight converts: W1 -> Btg[128 cols][512 k]; W2 -> Wt2[64 cols][128 k] ----
__global__ void k_wcvt(const float* __restrict__ W1, const float* __restrict__ W2,
                       unsigned short* __restrict__ Btg, unsigned short* __restrict__ Wt2) {
    int b = blockIdx.x;
    if (b < 256) {
        int id = b * 256 + threadIdx.x;   // 65536
        int kk = id >> 7, c = id & 127;
        float v = (kk < F_IN) ? W1[kk * F_HID + c] : 0.f;
        Btg[c * 512 + kk] = pack_bf16(v);
    } else {
        int id = (b - 256) * 256 + threadIdx.x;  // 8192 (32 blocks)
        int c = id >> 7, kk = id & 127;          // Wt2[col][k], cols 47..63 zero
        float v = (c < F_OUT) ? W2[kk * F_OUT + c] : 0.f;
        Wt2[c * 128 + kk] = pack_bf16(v);
    }
}

// ---------------- GEMM1 (bf16 MFMA, async dbuf, BK=32): hs16 = bf16((x @ W1) * dinv) ----
// LDS 20 KB (A 2x2KB + B 2x8KB) -> 8 blocks/CU at launch_bounds(256,8) = 32 waves/CU.
// Swizzle involution at 16B granularity: slot cg ^= (r&3), applied on BOTH the
// pre-swizzled gload_lds source and the ds_read side (rule: both-sides-or-neither).
// K accumulation order identical to BK=64 version -> absmax tripwire 0.03125.
#define BM 32
#define BK 32
__global__ __launch_bounds__(256, 8) void k_gemm1_mfma(const float* __restrict__ x,
                                                       const unsigned short* __restrict__ Btg,
                                                       const float* __restrict__ dinv,
                                                       unsigned short* __restrict__ hs16, int n) {
    __shared__ unsigned short As[2][BM * BK];     // 2 x 2 KB
    __shared__ unsigned short Bs[2][F_HID * BK];  // 2 x 8 KB
    int t = threadIdx.x;
    int row0 = blockIdx.x * BM;
    int w = t >> 6, l = t & 63;

    // A staging: threads 0..127, one 16B unit each (row ar, k-group acg of 4)
    int ar = t >> 2, acg = t & 3;
    int agrow = row0 + ar;
    int abyte = ar * 64 + ((acg * 16) ^ ((ar & 3) << 4));
    bool astage = (t < 128);

    f32x4 acc[2][2] = {};

#define LOAD_A(c, f0, f1)                                              \
    {                                                                  \
        int kbase = (c) * BK + acg * 8;                                \
        f0 = make_float4(0.f, 0.f, 0.f, 0.f);                          \
        f1 = make_float4(0.f, 0.f, 0.f, 0.f);                          \
        if (astage && agrow < n) {                                     \
            const float* p = x + (long)agrow * F_IN + kbase;           \
            if (kbase + 4 <= F_IN) f0 = *(const float4*)p;             \
            if (kbase + 8 <= F_IN) f1 = *(const float4*)(p + 4);       \
        }                                                              \
    }
    // B: 128 cols x 32 k = 8KB/chunk; 2 units of 16B per thread; linear LDS dest,
    // source k-group pre-swizzled by (cg ^ (r&3)).
#define STAGE_B(c, bsel)                                                         \
    {                                                                            \
        _Pragma("unroll")                                                        \
        for (int uu = 0; uu < 2; ++uu) {                                         \
            int u = t + uu * 256;                                                \
            int r = u >> 2, cg = u & 3;                                          \
            const unsigned short* gp =                                           \
                Btg + r * 512 + (c) * BK + ((cg ^ (r & 3)) * 8);                 \
            void* lp = (char*)&Bs[bsel][0] + (w * 1024 + uu * 4096);             \
            gload_lds16(gp, lp);                                                 \
        }                                                                        \
    }
#define WRITE_A(bsel, f0, f1)                                                    \
    if (astage) {                                                                \
        uint4 pk;                                                                \
        pk.x = pack_bf16x2(f0.x, f0.y);                                          \
        pk.y = pack_bf16x2(f0.z, f0.w);                                          \
        pk.z = pack_bf16x2(f1.x, f1.y);                                          \
        pk.w = pack_bf16x2(f1.z, f1.w);                                          \
        *(uint4*)((char*)&As[bsel][0] + abyte) = pk;                             \
    }

    {
        float4 a0, a1;
        STAGE_B(0, 0);
        LOAD_A(0, a0, a1);
        WRITE_A(0, a0, a1);
    }
    __syncthreads();

    int buf = 0;
    for (int c = 0; c < 16; ++c) {
        float4 na0, na1;
        if (c < 15) {
            STAGE_B(c + 1, buf ^ 1);
            LOAD_A(c + 1, na0, na1);
        }

        int lr = l & 15;
        int lkb = (l >> 4) * 16;   // byte offset of lane's 8-elem k group
        short8 af[2], bf[2];
#pragma unroll
        for (int mi = 0; mi < 2; ++mi) {
            int r = mi * 16 + lr;
            int byte = r * 64 + (lkb ^ ((r & 3) << 4));
            af[mi] = *(short8*)((char*)&As[buf][0] + byte);
        }
#pragma unroll
        for (int ni = 0; ni < 2; ++ni) {
            int r = w * 32 + ni * 16 + lr;
            int byte = r * 64 + (lkb ^ ((r & 3) << 4));
            bf[ni] = *(short8*)((char*)&Bs[buf][0] + byte);
        }
#pragma unroll
        for (int mi = 0; mi < 2; ++mi)
#pragma unroll
            for (int ni = 0; ni < 2; ++ni)
                acc[mi][ni] = __builtin_amdgcn_mfma_f32_16x16x32_bf16(
                    af[mi], bf[ni], acc[mi][ni], 0, 0, 0);

        if (c < 15) WRITE_A(buf ^ 1, na0, na1);
        __syncthreads();
        buf ^= 1;
    }

#pragma unroll
    for (int mi = 0; mi < 2; ++mi) {
        int rb = row0 + mi * 16 + (l >> 4) * 4;
        float dv[4];
#pragma unroll
        for (int reg = 0; reg < 4; ++reg)
            dv[reg] = (rb + reg < n) ? dinv[rb + reg] : 0.f;
#pragma unroll
        for (int ni = 0; ni < 2; ++ni) {
            int col = w * 32 + ni * 16 + (l & 15);
#pragma unroll
            for (int reg = 0; reg < 4; ++reg) {
                int row = rb + reg;
                if (row < n) hs16[(long)row * F_HID + col] = pack_bf16(acc[mi][ni][reg] * dv[reg]);
            }
        }
    }
#undef LOAD_A
#undef STAGE_B
#undef WRITE_A
}

// ---------------- gather layer 1 (shfl-batched, 8-deep MLP) ----------------
#define ACC4(v, u)                                   \
    v.x += __uint_as_float((u).x << 16);             \
    v.y += __uint_as_float((u).x & 0xFFFF0000u);     \
    v.z += __uint_as_float((u).y << 16);             \
    v.w += __uint_as_float((u).y & 0xFFFF0000u);

__global__ __launch_bounds__(256) void k_gather1(const unsigned short* __restrict__ hs16,
                                                 const int* __restrict__ rowptr,
                                                 const int* __restrict__ csr,
                                                 const float* __restrict__ dinv,
                                                 const float* __restrict__ b1,
                                                 unsigned short* __restrict__ h1, int n) {
    int tid = blockIdx.x * 256 + threadIdx.x;
    int node = tid >> 5;
    if (node >= n) return;
    int q = tid & 31;
    float4 v;
    {
        uint2 u = *(const uint2*)(hs16 + (long)node * F_HID + q * 4);  // self
        v.x = __uint_as_float(u.x << 16);
        v.y = __uint_as_float(u.x & 0xFFFF0000u);
        v.z = __uint_as_float(u.y << 16);
        v.w = __uint_as_float(u.y & 0xFFFF0000u);
    }
    int lo = rowptr[node];
    int cnt = rowptr[node + 1] - lo;
    for (int base = 0; base < cnt; base += 32) {
        int m = cnt - base; if (m > 32) m = 32;
        int myi = (base + q < cnt) ? csr[lo + base + q] : 0;
        int j = 0;
        for (; j + 8 <= m; j += 8) {
            uint2 u0 = *(const uint2*)(hs16 + (long)__shfl(myi, j + 0, 32) * F_HID + q * 4);
            uint2 u1 = *(const uint2*)(hs16 + (long)__shfl(myi, j + 1, 32) * F_HID + q * 4);
            uint2 u2 = *(const uint2*)(hs16 + (long)__shfl(myi, j + 2, 32) * F_HID + q * 4);
            uint2 u3 = *(const uint2*)(hs16 + (long)__shfl(myi, j + 3, 32) * F_HID + q * 4);
            uint2 u4 = *(const uint2*)(hs16 + (long)__shfl(myi, j + 4, 32) * F_HID + q * 4);
            uint2 u5 = *(const uint2*)(hs16 + (long)__shfl(myi, j + 5, 32) * F_HID + q * 4);
            uint2 u6 = *(const uint2*)(hs16 + (long)__shfl(myi, j + 6, 32) * F_HID + q * 4);
            uint2 u7 = *(const uint2*)(hs16 + (long)__shfl(myi, j + 7, 32) * F_HID + q * 4);
            ACC4(v, u0); ACC4(v, u1); ACC4(v, u2); ACC4(v, u3);
            ACC4(v, u4); ACC4(v, u5); ACC4(v, u6); ACC4(v, u7);
        }
        for (; j + 4 <= m; j += 4) {
            uint2 u0 = *(const uint2*)(hs16 + (long)__shfl(myi, j + 0, 32) * F_HID + q * 4);
            uint2 u1 = *(const uint2*)(hs16 + (long)__shfl(myi, j + 1, 32) * F_HID + q * 4);
            uint2 u2 = *(const uint2*)(hs16 + (long)__shfl(myi, j + 2, 32) * F_HID + q * 4);
            uint2 u3 = *(const uint2*)(hs16 + (long)__shfl(myi, j + 3, 32) * F_HID + q * 4);
            ACC4(v, u0); ACC4(v, u1); ACC4(v, u2); ACC4(v, u3);
        }
        for (; j < m; ++j) {
            uint2 u0 = *(const uint2*)(hs16 + (long)__shfl(myi, j, 32) * F_HID + q * 4);
            ACC4(v, u0);
        }
    }
    float dv = dinv[node];
    float4 bb = *(const float4*)&b1[q * 4];
    float r0 = fmaxf(dv * v.x + bb.x, 0.f);
    float r1 = fmaxf(dv * v.y + bb.y, 0.f);
    float r2 = fmaxf(dv * v.z + bb.z, 0.f);
    float r3 = fmaxf(dv * v.w + bb.w, 0.f);
    uint2 o;
    o.x = pack_bf16x2(r0, r1);
    o.y = pack_bf16x2(r2, r3);
    *(uint2*)(h1 + (long)node * F_HID + q * 4) = o;
}

// ---------------- GEMM2 (bf16 MFMA, no LDS): hs2 = bf16((h1 @ W2) * dinv), 64-col pad ----
__global__ __launch_bounds__(256, 4) void k_gemm2_mfma(const unsigned short* __restrict__ h1,
                                                       const unsigned short* __restrict__ Wt2,
                                                       const float* __restrict__ dinv,
                                                       unsigned short* __restrict__ hs2, int n) {
    int t = threadIdx.x, w = t >> 6, l = t & 63;
    int row0 = blockIdx.x * 32 + (w & 1) * 16;
    int col0 = (w >> 1) * 32;
    int lr = l & 15, lk = (l >> 4) * 8;

    short8 bf[2][4];
#pragma unroll
    for (int nf = 0; nf < 2; ++nf)
#pragma unroll
        for (int ks = 0; ks < 4; ++ks)
            bf[nf][ks] = *(const short8*)(Wt2 + (col0 + nf * 16 + lr) * 128 + ks * 32 + lk);

    int arow = row0 + lr;
    const short8 z8 = {};
    f32x4 acc[2] = {};
#pragma unroll
    for (int ks = 0; ks < 4; ++ks) {
        short8 af = (arow < n) ? *(const short8*)(h1 + (long)arow * F_HID + ks * 32 + lk) : z8;
#pragma unroll
        for (int nf = 0; nf < 2; ++nf)
            acc[nf] = __builtin_amdgcn_mfma_f32_16x16x32_bf16(af, bf[nf][ks], acc[nf], 0, 0, 0);
    }

    int rb = row0 + (l >> 4) * 4;
#pragma unroll
    for (int nf = 0; nf < 2; ++nf) {
        int col = col0 + nf * 16 + lr;
#pragma unroll
        for (int reg = 0; reg < 4; ++reg) {
            int row = rb + reg;
            if (row < n) hs2[(long)row * 64 + col] = pack_bf16(acc[nf][reg] * dinv[row]);
        }
    }
}

// ---------------- gather layer 2 + bias + log_softmax (shfl-batched, 8-deep) ----------------
#define ACC2(v0, v1, u)                              \
    v0 += __uint_as_float((u) << 16);                \
    v1 += __uint_as_float((u) & 0xFFFF0000u);

__global__ __launch_bounds__(256) void k_out(const unsigned short* __restrict__ hs2,
                                             const int* __restrict__ rowptr,
                                             const int* __restrict__ csr,
                                             const float* __restrict__ dinv,
                                             const float* __restrict__ b2,
                                             float* __restrict__ out, int n) {
    int tid = blockIdx.x * 256 + threadIdx.x;
    int node = tid >> 5;
    if (node >= n) return;
    int q = tid & 31;
    int c0 = 2 * q, c1 = 2 * q + 1;
    float v0, v1;
    {
        unsigned u = *(const unsigned*)(hs2 + (long)node * 64 + c0);  // self
        v0 = __uint_as_float(u << 16);
        v1 = __uint_as_float(u & 0xFFFF0000u);
    }
    int lo = rowptr[node];
    int cnt = rowptr[node + 1] - lo;
    for (int base = 0; base < cnt; base += 32) {
        int m = cnt - base; if (m > 32) m = 32;
        int myi = (base + q < cnt) ? csr[lo + base + q] : 0;
        int j = 0;
        for (; j + 8 <= m; j += 8) {
            unsigned u0 = *(const unsigned*)(hs2 + (long)__shfl(myi, j + 0, 32) * 64 + c0);
            unsigned u1 = *(const unsigned*)(hs2 + (long)__shfl(myi, j + 1, 32) * 64 + c0);
            unsigned u2 = *(const unsigned*)(hs2 + (long)__shfl(myi, j + 2, 32) * 64 + c0);
            unsigned u3 = *(const unsigned*)(hs2 + (long)__shfl(myi, j + 3, 32) * 64 + c0);
            unsigned u4 = *(const unsigned*)(hs2 + (long)__shfl(myi, j + 4, 32) * 64 + c0);
            unsigned u5 = *(const unsigned*)(hs2 + (long)__shfl(myi, j + 5, 32) * 64 + c0);
            unsigned u6 = *(const unsigned*)(hs2 + (long)__shfl(myi, j + 6, 32) * 64 + c0);
            unsigned u7 = *(const unsigned*)(hs2 + (long)__shfl(myi, j + 7, 32) * 64 + c0);
            ACC2(v0, v1, u0); ACC2(v0, v1, u1); ACC2(v0, v1, u2); ACC2(v0, v1, u3);
            ACC2(v0, v1, u4); ACC2(v0, v1, u5); ACC2(v0, v1, u6); ACC2(v0, v1, u7);
        }
        for (; j + 4 <= m; j += 4) {
            unsigned u0 = *(const unsigned*)(hs2 + (long)__shfl(myi, j + 0, 32) * 64 + c0);
            unsigned u1 = *(const unsigned*)(hs2 + (long)__shfl(myi, j + 1, 32) * 64 + c0);
            unsigned u2 = *(const unsigned*)(hs2 + (long)__shfl(myi, j + 2, 32) * 64 + c0);
            unsigned u3 = *(const unsigned*)(hs2 + (long)__shfl(myi, j + 3, 32) * 64 + c0);
            ACC2(v0, v1, u0); ACC2(v0, v1, u1); ACC2(v0, v1, u2); ACC2(v0, v1, u3);
        }
        for (; j < m; ++j) {
            unsigned u0 = *(const unsigned*)(hs2 + (long)__shfl(myi, j, 32) * 64 + c0);
            ACC2(v0, v1, u0);
        }
    }
    float dv = dinv[node];
    float z0 = (c0 < F_OUT) ? v0 * dv + b2[c0] : -INFINITY;
    float z1 = (c1 < F_OUT) ? v1 * dv + b2[c1] : -INFINITY;
    float m = fmaxf(z0, z1);
#pragma unroll
    for (int o = 16; o; o >>= 1) m = fmaxf(m, __shfl_xor(m, o));
    float sum = ((c0 < F_OUT) ? __expf(z0 - m) : 0.f) + ((c1 < F_OUT) ? __expf(z1 - m) : 0.f);
#pragma unroll
    for (int o = 16; o; o >>= 1) sum += __shfl_xor(sum, o);
    float ls = logf(sum) + m;
    if (c0 < F_OUT) out[(long)node * F_OUT + c0] = z0 - ls;
    if (c1 < F_OUT) out[(long)node * F_OUT + c1] = z1 - ls;
}

extern "C" void kernel_launch(void* const* d_in, const int* in_sizes, int n_in,
                              void* d_out, int out_size, void* d_ws, size_t ws_size,
                              hipStream_t stream) {
    const float* x  = (const float*)d_in[0];
    const float* W1 = (const float*)d_in[1];
    const float* b1 = (const float*)d_in[2];
    const float* W2 = (const float*)d_in[3];
    const float* b2 = (const float*)d_in[4];
    const int*   ei = (const int*)d_in[5];

    int n = in_sizes[0] / F_IN;      // 50000
    int E = in_sizes[5] / 2;         // 800000
    float* out = (float*)d_out;

    // workspace layout
    char* ws = (char*)d_ws;
    float* dinv   = (float*)(ws + 0);          // 200 KB
    int*   ecnt   = (int*)  (ws + 200704);
    int*   rowptr = (int*)  (ws + 401408);     // n+1 ints
    int*   cur    = (int*)  (ws + 602112);     // dead after k_fill; Btg aliases it
    unsigned short* Btg = (unsigned short*)(ws + 602112);  // 128 KB (ends 733184)
    int*   bsum   = (int*)  (ws + 733184);
    unsigned short* Wt2 = (unsigned short*)(ws + 741376);  // 16 KB (ends 757760)
    int*   csr    = (int*)  (ws + 802816);     // 3.2 MB
    unsigned short* hs16  = (unsigned short*)(ws + 4003840);   // 12.8 MB
    unsigned short* hs2   = (unsigned short*)(ws + 16804864);  // 6.4 MB
    unsigned short* h1    = (unsigned short*)(ws + 29603840);  // 12.8 MB

    int sb = (n + 1023) / 1024;                 // 49 scan blocks (<=64 required)
    hipMemsetAsync(ecnt, 0, (size_t)n * sizeof(int), stream);
    k_deg_count<<<1024, 256, 0, stream>>>(ei, ecnt, E, n);
    k_scanA<<<sb, 1024, 0, stream>>>(ecnt, rowptr, bsum, dinv, n);
    k_scanC<<<sb, 1024, 0, stream>>>(rowptr, cur, bsum, n, sb);
    k_fill<<<1024, 256, 0, stream>>>(ei, cur, csr, E, n);
    k_wcvt<<<288, 256, 0, stream>>>(W1, W2, Btg, Wt2);

    k_gemm1_mfma<<<(n + BM - 1) / BM, 256, 0, stream>>>(x, Btg, dinv, hs16, n);
    k_gather1<<<(n * 32 + 255) / 256, 256, 0, stream>>>(hs16, rowptr, csr, dinv, b1, h1, n);
    k_gemm2_mfma<<<(n + 31) / 32, 256, 0, stream>>>(h1, Wt2, dinv, hs2, n);
    k_out<<<(n * 32 + 255) / 256, 256, 0, stream>>>(hs2, rowptr, csr, dinv, b2, out, n);
}

// Round 18
// 180.626 us; speedup vs baseline: 1.0415x; 1.0415x over previous
//
#include <hip/hip_runtime.h>
#include <math.h>

#define F_IN 500
#define F_HID 128
#define F_OUT 47
#define NGRP 8

typedef __attribute__((ext_vector_type(8))) short short8;
typedef __attribute__((ext_vector_type(4))) float f32x4;

__device__ inline unsigned pack_bf16x2(float a, float b) {
    unsigned ua = __float_as_uint(a), ub = __float_as_uint(b);
    ua = (ua + 0x7FFFu + ((ua >> 16) & 1u)) >> 16;
    ub = (ub + 0x7FFFu + ((ub >> 16) & 1u)) >> 16;
    return ua | (ub << 16);
}
__device__ inline unsigned short pack_bf16(float a) {
    unsigned u = __float_as_uint(a);
    return (unsigned short)((u + 0x7FFFu + ((u >> 16) & 1u)) >> 16);
}

// async global->LDS, 16B per lane, dest = wave-uniform base + lane*16
__device__ __forceinline__ void gload_lds16(const void* g, void* l) {
    __builtin_amdgcn_global_load_lds(
        (const __attribute__((address_space(1))) unsigned int*)g,
        (__attribute__((address_space(3))) unsigned int*)l, 16, 0, 0);
}

// ---------------- degree / norm / CSR build ----------------
// XCD-partitioned + int4-vectorized: group g = blockIdx&7 handles dst in its n/8 slice.
__global__ void k_deg_count(const int* __restrict__ ei, int* __restrict__ ecnt,
                            int E, int n) {
    int g = blockIdx.x & (NGRP - 1);
    int bi = blockIdx.x >> 3;
    int nbg = gridDim.x >> 3;
    int lo = (int)((long)g * n / NGRP), hi = (int)((long)(g + 1) * n / NGRP);
    const int4* dst4 = (const int4*)(ei + E);
    int E4 = E >> 2;
    for (int e4 = bi * 256 + threadIdx.x; e4 < E4; e4 += nbg * 256) {
        int4 d = dst4[e4];
        if (d.x >= lo && d.x < hi) atomicAdd(&ecnt[d.x], 1);
        if (d.y >= lo && d.y < hi) atomicAdd(&ecnt[d.y], 1);
        if (d.z >= lo && d.z < hi) atomicAdd(&ecnt[d.z], 1);
        if (d.w >= lo && d.w < hi) atomicAdd(&ecnt[d.w], 1);
    }
    for (int e = E4 * 4 + bi * 256 + threadIdx.x; e < E; e += nbg * 256) {
        int d = ei[E + e];
        if (d >= lo && d < hi) atomicAdd(&ecnt[d], 1);
    }
}

// ---------------- scan phase A (+ dinv fused) ----------------
__global__ __launch_bounds__(1024) void k_scanA(const int* __restrict__ ecnt,
                                                int* __restrict__ rowptr,
                                                int* __restrict__ bsum,
                                                float* __restrict__ dinv, int n) {
    __shared__ int tmp[1024];
    int t = threadIdx.x;
    int gid = blockIdx.x * 1024 + t;
    int v = (gid < n) ? ecnt[gid] : 0;
    if (gid < n) dinv[gid] = rsqrtf((float)(v + 1));  // +1 self-loop
    tmp[t] = v;
    __syncthreads();
    for (int off = 1; off < 1024; off <<= 1) {
        int u = (t >= off) ? tmp[t - off] : 0;
        __syncthreads();
        tmp[t] += u;
        __syncthreads();
    }
    if (gid < n) rowptr[gid] = tmp[t] - v;
    if (t == 1023) bsum[blockIdx.x] = tmp[1023];
}

// ---------------- scan phase C (self-contained: scans bsum per block; nb<=64) ----------
__global__ __launch_bounds__(1024) void k_scanC(int* __restrict__ rowptr,
                                                int* __restrict__ cur,
                                                const int* __restrict__ bsum,
                                                int n, int nb) {
    __shared__ int s_off, s_tot;
    int t = threadIdx.x;
    if (t < 64) {
        int v = (t < nb) ? bsum[t] : 0;
        int inc = v;
#pragma unroll
        for (int off = 1; off < 64; off <<= 1) {
            int u = __shfl_up(inc, off);
            if (t >= off) inc += u;
        }
        if (t == (int)blockIdx.x) s_off = inc - v;  // exclusive offset for this block
        if (t == nb - 1) s_tot = inc;               // grand total
    }
    __syncthreads();
    int gid = blockIdx.x * 1024 + t;
    if (gid < n) {
        int v = rowptr[gid] + s_off;
        rowptr[gid] = v;
        cur[gid] = v;
    } else if (gid == n) {
        rowptr[n] = s_tot;
    }
}

// XCD-partitioned + int4-vectorized CSR fill
__global__ void k_fill(const int* __restrict__ ei, int* __restrict__ cur,
                       int* __restrict__ csr, int E, int n) {
    int g = blockIdx.x & (NGRP - 1);
    int bi = blockIdx.x >> 3;
    int nbg = gridDim.x >> 3;
    int lo = (int)((long)g * n / NGRP), hi = (int)((long)(g + 1) * n / NGRP);
    const int4* dst4 = (const int4*)(ei + E);
    const int4* src4 = (const int4*)ei;
    int E4 = E >> 2;
    for (int e4 = bi * 256 + threadIdx.x; e4 < E4; e4 += nbg * 256) {
        int4 d = dst4[e4];
        int4 s = src4[e4];
        if (d.x >= lo && d.x < hi) csr[atomicAdd(&cur[d.x], 1)] = s.x;
        if (d.y >= lo && d.y < hi) csr[atomicAdd(&cur[d.y], 1)] = s.y;
        if (d.z >= lo && d.z < hi) csr[atomicAdd(&cur[d.z], 1)] = s.z;
        if (d.w >= lo && d.w < hi) csr[atomicAdd(&cur[d.w], 1)] = s.w;
    }
    for (int e = E4 * 4 + bi * 256 + threadIdx.x; e < E; e += nbg * 256) {
        int d = ei[E + e];
        if (d >= lo && d < hi) csr[atomicAdd(&cur[d], 1)] = ei[e];
    }
}

// ---------------- weight converts: W1 -> Btg[128 cols][512 k]; W2 -> Wt2[64 cols][128 k] ----
__global__ void k_wcvt(const float* __restrict__ W1, const float* __restrict__ W2,
                       unsigned short* __restrict__ Btg, unsigned short* __restrict__ Wt2) {
    int b = blockIdx.x;
    if (b < 256) {
        int id = b * 256 + threadIdx.x;   // 65536
        int kk = id >> 7, c = id & 127;
        float v = (kk < F_IN) ? W1[kk * F_HID + c] : 0.f;
        Btg[c * 512 + kk] = pack_bf16(v);
    } else {
        int id = (b - 256) * 256 + threadIdx.x;  // 8192 (32 blocks)
        int c = id >> 7, kk = id & 127;          // Wt2[col][k], cols 47..63 zero
        float v = (c < F_OUT) ? W2[kk * F_OUT + c] : 0.f;
        Wt2[c * 128 + kk] = pack_bf16(v);
    }
}

// ---------------- GEMM1 (bf16 MFMA, async dbuf pipeline — best measured config) ----------
// BM=32/BK=64, 40 KB LDS -> 4 blocks/CU; zero bank conflicts (verified R14/R16 PMC).
#define BM 32
#define BK 64
__global__ __launch_bounds__(256, 4) void k_gemm1_mfma(const float* __restrict__ x,
                                                       const unsigned short* __restrict__ Btg,
                                                       const float* __restrict__ dinv,
                                                       unsigned short* __restrict__ hs16, int n) {
    __shared__ unsigned short As[2][BM * BK];     // 2 x 4 KB, XOR-swizzled
    __shared__ unsigned short Bs[2][F_HID * BK];  // 2 x 16 KB, XOR-swizzled content
    int t = threadIdx.x;
    int row0 = blockIdx.x * BM;
    int w = t >> 6, l = t & 63;

    int ar = t >> 3, acg = t & 7;
    int agrow = row0 + ar;
    int abyte = ar * 128 + ((acg * 16) ^ ((ar & 7) << 4));

    f32x4 acc[2][2] = {};

#define LOAD_A(c, f0, f1)                                              \
    {                                                                  \
        int kbase = (c) * BK + acg * 8;                                \
        f0 = make_float4(0.f, 0.f, 0.f, 0.f);                          \
        f1 = make_float4(0.f, 0.f, 0.f, 0.f);                          \
        if (agrow < n) {                                               \
            const float* p = x + (long)agrow * F_IN + kbase;           \
            if (kbase + 4 <= F_IN) f0 = *(const float4*)p;             \
            if (kbase + 8 <= F_IN) f1 = *(const float4*)(p + 4);       \
        }                                                              \
    }
#define STAGE_B(c, bsel)                                                         \
    {                                                                            \
        _Pragma("unroll")                                                        \
        for (int uu = 0; uu < 4; ++uu) {                                         \
            int u = t + uu * 256;                                                \
            int r = u >> 3, cg = u & 7;                                          \
            const unsigned short* gp =                                           \
                Btg + r * 512 + (c) * BK + ((cg ^ (r & 7)) * 8);                 \
            void* lp = (char*)&Bs[bsel][0] + (w * 1024 + uu * 4096);             \
            gload_lds16(gp, lp);                                                 \
        }                                                                        \
    }
#define WRITE_A(bsel, f0, f1)                                                    \
    {                                                                            \
        uint4 pk;                                                                \
        pk.x = pack_bf16x2(f0.x, f0.y);                                          \
        pk.y = pack_bf16x2(f0.z, f0.w);                                          \
        pk.z = pack_bf16x2(f1.x, f1.y);                                          \
        pk.w = pack_bf16x2(f1.z, f1.w);                                          \
        *(uint4*)((char*)&As[bsel][0] + abyte) = pk;                             \
    }

    {
        float4 a0, a1;
        STAGE_B(0, 0);
        LOAD_A(0, a0, a1);
        WRITE_A(0, a0, a1);
    }
    __syncthreads();

    int buf = 0;
    for (int c = 0; c < 8; ++c) {
        float4 na0, na1;
        if (c < 7) {
            STAGE_B(c + 1, buf ^ 1);
            LOAD_A(c + 1, na0, na1);
        }

        int lr = l & 15;
        int lkb = (l >> 4) * 16;
        short8 af[2][2], bf[2][2];
#pragma unroll
        for (int mi = 0; mi < 2; ++mi)
#pragma unroll
            for (int ks = 0; ks < 2; ++ks) {
                int r = mi * 16 + lr;
                int byte = r * 128 + (((ks * 64) + lkb) ^ ((r & 7) << 4));
                af[mi][ks] = *(short8*)((char*)&As[buf][0] + byte);
            }
#pragma unroll
        for (int ni = 0; ni < 2; ++ni)
#pragma unroll
            for (int ks = 0; ks < 2; ++ks) {
                int r = w * 32 + ni * 16 + lr;
                int byte = r * 128 + (((ks * 64) + lkb) ^ ((r & 7) << 4));
                bf[ni][ks] = *(short8*)((char*)&Bs[buf][0] + byte);
            }
#pragma unroll
        for (int mi = 0; mi < 2; ++mi)
#pragma unroll
            for (int ni = 0; ni < 2; ++ni)
#pragma unroll
                for (int ks = 0; ks < 2; ++ks)
                    acc[mi][ni] = __builtin_amdgcn_mfma_f32_16x16x32_bf16(
                        af[mi][ks], bf[ni][ks], acc[mi][ni], 0, 0, 0);

        if (c < 7) WRITE_A(buf ^ 1, na0, na1);
        __syncthreads();
        buf ^= 1;
    }

#pragma unroll
    for (int mi = 0; mi < 2; ++mi) {
        int rb = row0 + mi * 16 + (l >> 4) * 4;
        float dv[4];
#pragma unroll
        for (int reg = 0; reg < 4; ++reg)
            dv[reg] = (rb + reg < n) ? dinv[rb + reg] : 0.f;
#pragma unroll
        for (int ni = 0; ni < 2; ++ni) {
            int col = w * 32 + ni * 16 + (l & 15);
#pragma unroll
            for (int reg = 0; reg < 4; ++reg) {
                int row = rb + reg;
                if (row < n) hs16[(long)row * F_HID + col] = pack_bf16(acc[mi][ni][reg] * dv[reg]);
            }
        }
    }
#undef LOAD_A
#undef STAGE_B
#undef WRITE_A
}

// ---------------- gather layer 1 (shfl-batched, 8-deep MLP) ----------------
#define ACC4(v, u)                                   \
    v.x += __uint_as_float((u).x << 16);             \
    v.y += __uint_as_float((u).x & 0xFFFF0000u);     \
    v.z += __uint_as_float((u).y << 16);             \
    v.w += __uint_as_float((u).y & 0xFFFF0000u);

__global__ __launch_bounds__(256) void k_gather1(const unsigned short* __restrict__ hs16,
                                                 const int* __restrict__ rowptr,
                                                 const int* __restrict__ csr,
                                                 const float* __restrict__ dinv,
                                                 const float* __restrict__ b1,
                                                 unsigned short* __restrict__ h1, int n) {
    int tid = blockIdx.x * 256 + threadIdx.x;
    int node = tid >> 5;
    if (node >= n) return;
    int q = tid & 31;
    float4 v;
    {
        uint2 u = *(const uint2*)(hs16 + (long)node * F_HID + q * 4);  // self
        v.x = __uint_as_float(u.x << 16);
        v.y = __uint_as_float(u.x & 0xFFFF0000u);
        v.z = __uint_as_float(u.y << 16);
        v.w = __uint_as_float(u.y & 0xFFFF0000u);
    }
    int lo = rowptr[node];
    int cnt = rowptr[node + 1] - lo;
    for (int base = 0; base < cnt; base += 32) {
        int m = cnt - base; if (m > 32) m = 32;
        int myi = (base + q < cnt) ? csr[lo + base + q] : 0;
        int j = 0;
        for (; j + 8 <= m; j += 8) {
            uint2 u0 = *(const uint2*)(hs16 + (long)__shfl(myi, j + 0, 32) * F_HID + q * 4);
            uint2 u1 = *(const uint2*)(hs16 + (long)__shfl(myi, j + 1, 32) * F_HID + q * 4);
            uint2 u2 = *(const uint2*)(hs16 + (long)__shfl(myi, j + 2, 32) * F_HID + q * 4);
            uint2 u3 = *(const uint2*)(hs16 + (long)__shfl(myi, j + 3, 32) * F_HID + q * 4);
            uint2 u4 = *(const uint2*)(hs16 + (long)__shfl(myi, j + 4, 32) * F_HID + q * 4);
            uint2 u5 = *(const uint2*)(hs16 + (long)__shfl(myi, j + 5, 32) * F_HID + q * 4);
            uint2 u6 = *(const uint2*)(hs16 + (long)__shfl(myi, j + 6, 32) * F_HID + q * 4);
            uint2 u7 = *(const uint2*)(hs16 + (long)__shfl(myi, j + 7, 32) * F_HID + q * 4);
            ACC4(v, u0); ACC4(v, u1); ACC4(v, u2); ACC4(v, u3);
            ACC4(v, u4); ACC4(v, u5); ACC4(v, u6); ACC4(v, u7);
        }
        for (; j + 4 <= m; j += 4) {
            uint2 u0 = *(const uint2*)(hs16 + (long)__shfl(myi, j + 0, 32) * F_HID + q * 4);
            uint2 u1 = *(const uint2*)(hs16 + (long)__shfl(myi, j + 1, 32) * F_HID + q * 4);
            uint2 u2 = *(const uint2*)(hs16 + (long)__shfl(myi, j + 2, 32) * F_HID + q * 4);
            uint2 u3 = *(const uint2*)(hs16 + (long)__shfl(myi, j + 3, 32) * F_HID + q * 4);
            ACC4(v, u0); ACC4(v, u1); ACC4(v, u2); ACC4(v, u3);
        }
        for (; j < m; ++j) {
            uint2 u0 = *(const uint2*)(hs16 + (long)__shfl(myi, j, 32) * F_HID + q * 4);
            ACC4(v, u0);
        }
    }
    float dv = dinv[node];
    float4 bb = *(const float4*)&b1[q * 4];
    float r0 = fmaxf(dv * v.x + bb.x, 0.f);
    float r1 = fmaxf(dv * v.y + bb.y, 0.f);
    float r2 = fmaxf(dv * v.z + bb.z, 0.f);
    float r3 = fmaxf(dv * v.w + bb.w, 0.f);
    uint2 o;
    o.x = pack_bf16x2(r0, r1);
    o.y = pack_bf16x2(r2, r3);
    *(uint2*)(h1 + (long)node * F_HID + q * 4) = o;
}

// ---------------- GEMM2 (bf16 MFMA, no LDS): hs2 = bf16((h1 @ W2) * dinv), 64-col pad ----
__global__ __launch_bounds__(256, 4) void k_gemm2_mfma(const unsigned short* __restrict__ h1,
                                                       const unsigned short* __restrict__ Wt2,
                                                       const float* __restrict__ dinv,
                                                       unsigned short* __restrict__ hs2, int n) {
    int t = threadIdx.x, w = t >> 6, l = t & 63;
    int row0 = blockIdx.x * 32 + (w & 1) * 16;
    int col0 = (w >> 1) * 32;
    int lr = l & 15, lk = (l >> 4) * 8;

    short8 bf[2][4];
#pragma unroll
    for (int nf = 0; nf < 2; ++nf)
#pragma unroll
        for (int ks = 0; ks < 4; ++ks)
            bf[nf][ks] = *(const short8*)(Wt2 + (col0 + nf * 16 + lr) * 128 + ks * 32 + lk);

    int arow = row0 + lr;
    const short8 z8 = {};
    f32x4 acc[2] = {};
#pragma unroll
    for (int ks = 0; ks < 4; ++ks) {
        short8 af = (arow < n) ? *(const short8*)(h1 + (long)arow * F_HID + ks * 32 + lk) : z8;
#pragma unroll
        for (int nf = 0; nf < 2; ++nf)
            acc[nf] = __builtin_amdgcn_mfma_f32_16x16x32_bf16(af, bf[nf][ks], acc[nf], 0, 0, 0);
    }

    int rb = row0 + (l >> 4) * 4;
#pragma unroll
    for (int nf = 0; nf < 2; ++nf) {
        int col = col0 + nf * 16 + lr;
#pragma unroll
        for (int reg = 0; reg < 4; ++reg) {
            int row = rb + reg;
            if (row < n) hs2[(long)row * 64 + col] = pack_bf16(acc[nf][reg] * dinv[row]);
        }
    }
}

// ---------------- gather layer 2 + bias + log_softmax (shfl-batched, 8-deep) ----------------
#define ACC2(v0, v1, u)                              \
    v0 += __uint_as_float((u) << 16);                \
    v1 += __uint_as_float((u) & 0xFFFF0000u);

__global__ __launch_bounds__(256) void k_out(const unsigned short* __restrict__ hs2,
                                             const int* __restrict__ rowptr,
                                             const int* __restrict__ csr,
                                             const float* __restrict__ dinv,
                                             const float* __restrict__ b2,
                                             float* __restrict__ out, int n) {
    int tid = blockIdx.x * 256 + threadIdx.x;
    int node = tid >> 5;
    if (node >= n) return;
    int q = tid & 31;
    int c0 = 2 * q, c1 = 2 * q + 1;
    float v0, v1;
    {
        unsigned u = *(const unsigned*)(hs2 + (long)node * 64 + c0);  // self
        v0 = __uint_as_float(u << 16);
        v1 = __uint_as_float(u & 0xFFFF0000u);
    }
    int lo = rowptr[node];
    int cnt = rowptr[node + 1] - lo;
    for (int base = 0; base < cnt; base += 32) {
        int m = cnt - base; if (m > 32) m = 32;
        int myi = (base + q < cnt) ? csr[lo + base + q] : 0;
        int j = 0;
        for (; j + 8 <= m; j += 8) {
            unsigned u0 = *(const unsigned*)(hs2 + (long)__shfl(myi, j + 0, 32) * 64 + c0);
            unsigned u1 = *(const unsigned*)(hs2 + (long)__shfl(myi, j + 1, 32) * 64 + c0);
            unsigned u2 = *(const unsigned*)(hs2 + (long)__shfl(myi, j + 2, 32) * 64 + c0);
            unsigned u3 = *(const unsigned*)(hs2 + (long)__shfl(myi, j + 3, 32) * 64 + c0);
            unsigned u4 = *(const unsigned*)(hs2 + (long)__shfl(myi, j + 4, 32) * 64 + c0);
            unsigned u5 = *(const unsigned*)(hs2 + (long)__shfl(myi, j + 5, 32) * 64 + c0);
            unsigned u6 = *(const unsigned*)(hs2 + (long)__shfl(myi, j + 6, 32) * 64 + c0);
            unsigned u7 = *(const unsigned*)(hs2 + (long)__shfl(myi, j + 7, 32) * 64 + c0);
            ACC2(v0, v1, u0); ACC2(v0, v1, u1); ACC2(v0, v1, u2); ACC2(v0, v1, u3);
            ACC2(v0, v1, u4); ACC2(v0, v1, u5); ACC2(v0, v1, u6); ACC2(v0, v1, u7);
        }
        for (; j + 4 <= m; j += 4) {
            unsigned u0 = *(const unsigned*)(hs2 + (long)__shfl(myi, j + 0, 32) * 64 + c0);
            unsigned u1 = *(const unsigned*)(hs2 + (long)__shfl(myi, j + 1, 32) * 64 + c0);
            unsigned u2 = *(const unsigned*)(hs2 + (long)__shfl(myi, j + 2, 32) * 64 + c0);
            unsigned u3 = *(const unsigned*)(hs2 + (long)__shfl(myi, j + 3, 32) * 64 + c0);
            ACC2(v0, v1, u0); ACC2(v0, v1, u1); ACC2(v0, v1, u2); ACC2(v0, v1, u3);
        }
        for (; j < m; ++j) {
            unsigned u0 = *(const unsigned*)(hs2 + (long)__shfl(myi, j, 32) * 64 + c0);
            ACC2(v0, v1, u0);
        }
    }
    float dv = dinv[node];
    float z0 = (c0 < F_OUT) ? v0 * dv + b2[c0] : -INFINITY;
    float z1 = (c1 < F_OUT) ? v1 * dv + b2[c1] : -INFINITY;
    float m = fmaxf(z0, z1);
#pragma unroll
    for (int o = 16; o; o >>= 1) m = fmaxf(m, __shfl_xor(m, o));
    float sum = ((c0 < F_OUT) ? __expf(z0 - m) : 0.f) + ((c1 < F_OUT) ? __expf(z1 - m) : 0.f);
#pragma unroll
    for (int o = 16; o; o >>= 1) sum += __shfl_xor(sum, o);
    float ls = logf(sum) + m;
    if (c0 < F_OUT) out[(long)node * F_OUT + c0] = z0 - ls;
    if (c1 < F_OUT) out[(long)node * F_OUT + c1] = z1 - ls;
}

extern "C" void kernel_launch(void* const* d_in, const int* in_sizes, int n_in,
                              void* d_out, int out_size, void* d_ws, size_t ws_size,
                              hipStream_t stream) {
    const float* x  = (const float*)d_in[0];
    const float* W1 = (const float*)d_in[1];
    const float* b1 = (const float*)d_in[2];
    const float* W2 = (const float*)d_in[3];
    const float* b2 = (const float*)d_in[4];
    const int*   ei = (const int*)d_in[5];

    int n = in_sizes[0] / F_IN;      // 50000
    int E = in_sizes[5] / 2;         // 800000
    float* out = (float*)d_out;

    // workspace layout
    char* ws = (char*)d_ws;
    float* dinv   = (float*)(ws + 0);          // 200 KB
    int*   ecnt   = (int*)  (ws + 200704);
    int*   rowptr = (int*)  (ws + 401408);     // n+1 ints
    int*   cur    = (int*)  (ws + 602112);     // dead after k_fill; Btg aliases it
    unsigned short* Btg = (unsigned short*)(ws + 602112);  // 128 KB (ends 733184)
    int*   bsum   = (int*)  (ws + 733184);
    unsigned short* Wt2 = (unsigned short*)(ws + 741376);  // 16 KB (ends 757760)
    int*   csr    = (int*)  (ws + 802816);     // 3.2 MB
    unsigned short* hs16  = (unsigned short*)(ws + 4003840);   // 12.8 MB
    unsigned short* hs2   = (unsigned short*)(ws + 16804864);  // 6.4 MB
    unsigned short* h1    = (unsigned short*)(ws + 29603840);  // 12.8 MB

    int sb = (n + 1023) / 1024;                 // 49 scan blocks (<=64 required)
    hipMemsetAsync(ecnt, 0, (size_t)n * sizeof(int), stream);
    k_deg_count<<<1024, 256, 0, stream>>>(ei, ecnt, E, n);
    k_scanA<<<sb, 1024, 0, stream>>>(ecnt, rowptr, bsum, dinv, n);
    k_scanC<<<sb, 1024, 0, stream>>>(rowptr, cur, bsum, n, sb);
    k_fill<<<1024, 256, 0, stream>>>(ei, cur, csr, E, n);
    k_wcvt<<<288, 256, 0, stream>>>(W1, W2, Btg, Wt2);

    k_gemm1_mfma<<<(n + BM - 1) / BM, 256, 0, stream>>>(x, Btg, dinv, hs16, n);
    k_gather1<<<(n * 32 + 255) / 256, 256, 0, stream>>>(hs16, rowptr, csr, dinv, b1, h1, n);
    k_gemm2_mfma<<<(n + 31) / 32, 256, 0, stream>>>(h1, Wt2, dinv, hs2, n);
    k_out<<<(n * 32 + 255) / 256, 256, 0, stream>>>(hs2, rowptr, csr, dinv, b2, out, n);
}